// Round 6
// baseline (345.787 us; speedup 1.0000x reference)
//
#include <hip/hip_runtime.h>
#include <math.h>
#include <stdint.h>

#define B_ 4
#define T_ 128
#define V_ 50257
#define D_ 512
#define NROWS 512           // B*T
#define GAMMA2_ 0.1f

#define KP 51200            // K padded (zero-filled) for clamp-free GEMM
#define KPB (KP * 2)        // bf16 row stride in bytes

// ---- Path B (R4 fallback) params
#define BK 32
#define KC 1600
#define SPLITK 32
#define NIT (KC / BK)
#define LDA 40
#define LDB 40
#define SLICE (NROWS * D_)  // 1 MB per slice

// ---- Path A params
#define SPLITK2 64
#define KC2 800             // 64*800 = 51200 = KP
#define NIT2 (KC2 / BK)     // 25

#define WS_PART_OFF 1024    // floats (Path B/C part offset)

// ---- Path A ws byte layout
#define EB_OFF    4096ull
#define WBT_OFF   (EB_OFF + (unsigned long long)NROWS * KP * 2)
#define PART2_OFF (WBT_OFF + (unsigned long long)D_ * KP * 2)
#define NEED_A    (PART2_OFF + (unsigned long long)SPLITK2 * SLICE * 4)
#define NEED_B    (4096ull + (unsigned long long)SPLITK * SLICE * 4)

typedef __attribute__((ext_vector_type(8))) short s8v;
typedef __attribute__((ext_vector_type(4))) float f4v;

__device__ inline unsigned int pack2bf(float f0, float f1) {
    unsigned int u0 = __float_as_uint(f0);
    unsigned int u1 = __float_as_uint(f1);
    u0 += 0x7fffu + ((u0 >> 16) & 1u);
    u1 += 0x7fffu + ((u1 >> 16) & 1u);
    return (u0 >> 16) | (u1 & 0xffff0000u);
}

__device__ inline float wave_reduce(float v) {
    #pragma unroll
    for (int o = 32; o > 0; o >>= 1) v += __shfl_down(v, o, 64);
    return v;
}

// CK-style direct global->LDS 16B copy (gfx950)
__device__ inline void gl_lds16(const void* gp, void* lp) {
    __builtin_amdgcn_global_load_lds(
        reinterpret_cast<const __attribute__((address_space(1))) unsigned int*>(
            reinterpret_cast<uintptr_t>(gp)),
        reinterpret_cast<__attribute__((address_space(3))) unsigned int*>(
            reinterpret_cast<uintptr_t>(lp)),
        16, 0, 0);
}

// ---------------- misc: nll, coverage, dec_len sums ----------------
__global__ void misc_kernel(const float* __restrict__ output_mle,
                            const float* __restrict__ attn,
                            const float* __restrict__ cover,
                            const int* __restrict__ trg,
                            const int* __restrict__ dec_mask,
                            const int* __restrict__ dec_len,
                            float* __restrict__ acc) {
    int bid = blockIdx.x;
    if (bid < 64) {
        float s = 0.f;
        const float4* a4 = (const float4*)attn;
        const float4* c4 = (const float4*)cover;
        for (int i4 = bid * 256 + threadIdx.x; i4 < 65536; i4 += 64 * 256) {
            float4 a = a4[i4];
            float4 c = c4[i4];
            int b = i4 >> 14;
            int t = (i4 << 2) & (T_ - 1);
            int4 m = *(const int4*)&dec_mask[(b << 7) + t];
            s += m.x ? 0.f : fminf(a.x, c.x);
            s += m.y ? 0.f : fminf(a.y, c.y);
            s += m.z ? 0.f : fminf(a.z, c.z);
            s += m.w ? 0.f : fminf(a.w, c.w);
        }
        s = wave_reduce(s);
        if ((threadIdx.x & 63) == 0) atomicAdd(&acc[2], s);
    } else {
        float lp = 0.f, cnt = 0.f;
        for (int i = threadIdx.x; i < NROWS; i += 256) {
            int tg = trg[i];
            if (tg != 0) {
                lp += __logf(output_mle[(size_t)i * V_ + tg]);
                cnt += 1.f;
            }
        }
        lp = wave_reduce(lp); cnt = wave_reduce(cnt);
        if ((threadIdx.x & 63) == 0) { atomicAdd(&acc[0], lp); atomicAdd(&acc[1], cnt); }
        if (threadIdx.x < B_) atomicAdd(&acc[3], (float)dec_len[threadIdx.x]);
    }
}

// ---------------- conv_e: Eb[row][k] = bf16(exp(X[row][k])), zero-pad to KP ----
__global__ void conv_e_kernel(const float* __restrict__ X, uint4* __restrict__ Eb) {
    const int CPR = KP / 8;                 // 6400 chunks per row
    const int total = NROWS * CPR;
    for (int idx = blockIdx.x * 256 + threadIdx.x; idx < total; idx += gridDim.x * 256) {
        int row = idx / CPR;
        int k   = (idx - row * CPR) * 8;
        const float* xp = X + (size_t)row * V_ + k;
        float f[8];
        if (k + 8 <= V_) {
            float4 v0 = *(const float4*)xp;
            float4 v1 = *(const float4*)(xp + 4);
            f[0] = v0.x; f[1] = v0.y; f[2] = v0.z; f[3] = v0.w;
            f[4] = v1.x; f[5] = v1.y; f[6] = v1.z; f[7] = v1.w;
            #pragma unroll
            for (int j = 0; j < 8; j++) f[j] = __expf(f[j]);
        } else {
            #pragma unroll
            for (int j = 0; j < 8; j++) f[j] = (k + j < V_) ? __expf(xp[j]) : 0.f;
        }
        uint4 o;
        o.x = pack2bf(f[0], f[1]); o.y = pack2bf(f[2], f[3]);
        o.z = pack2bf(f[4], f[5]); o.w = pack2bf(f[6], f[7]);
        Eb[idx] = o;
    }
}

// ---------------- conv_w: Wbt[n][k] = bf16(W[k][n]), zero-pad k to KP ----------
__global__ void conv_w_kernel(const float* __restrict__ W, unsigned int* __restrict__ Wbt) {
    __shared__ float tileT[64][65];
    int bid = blockIdx.x;
    int kt = bid % (KP / 64), nt = bid / (KP / 64);
    int k0 = kt * 64, n0 = nt * 64;
    int t = threadIdx.x;
    int kk = t >> 2, nj = (t & 3) * 16;
    float v[16];
    if (k0 + kk < V_) {
        const float4* wp = (const float4*)(W + (size_t)(k0 + kk) * D_ + n0 + nj);
        #pragma unroll
        for (int q = 0; q < 4; q++) {
            float4 x = wp[q];
            v[q * 4] = x.x; v[q * 4 + 1] = x.y; v[q * 4 + 2] = x.z; v[q * 4 + 3] = x.w;
        }
    } else {
        #pragma unroll
        for (int j = 0; j < 16; j++) v[j] = 0.f;
    }
    #pragma unroll
    for (int j = 0; j < 16; j++) tileT[nj + j][kk] = v[j];
    __syncthreads();
    int n = t >> 2, kq = (t & 3) * 16;
    unsigned int o[8];
    #pragma unroll
    for (int p = 0; p < 8; p++)
        o[p] = pack2bf(tileT[n][kq + 2 * p], tileT[n][kq + 2 * p + 1]);
    unsigned int* dst = Wbt + ((size_t)(n0 + n) * KP + k0 + kq) / 2;
    *(uint4*)dst       = *(const uint4*)&o[0];
    *(uint4*)(dst + 4) = *(const uint4*)&o[4];
}

// ---------------- gemm2: m97-style bf16 MFMA, global_load_lds staging ----------
__launch_bounds__(256)
__global__ void gemm2_kernel(const unsigned char* __restrict__ Eb,
                             const unsigned char* __restrict__ Wbt,
                             float* __restrict__ part) {
    __shared__ __align__(16) unsigned char As[128 * 64];   // [row][32k] bf16
    __shared__ __align__(16) unsigned char Bs[128 * 64];   // [col][32k] bf16

    const int bx   = blockIdx.x;
    const int tile = bx & 15;
    const int s    = bx >> 4;
    const int i0   = (tile & 3) * 128;
    const int d0   = (tile >> 2) * 128;
    const int ks   = s * KC2;

    const int tid  = threadIdx.x;
    const int lane = tid & 63;
    const int wave = tid >> 6;
    const int wm   = (wave & 1) * 64;
    const int wn   = (wave >> 1) * 64;
    const int l15  = lane & 15;
    const int l4   = lane >> 4;

    const int srow = tid >> 2;          // 0..63
    const int koct = tid & 3;           // 8-elem octet within BK=32

    const unsigned char* ga0 = Eb  + (size_t)(i0 + srow) * KPB + (size_t)(ks + koct * 8) * 2;
    const unsigned char* ga1 = ga0 + (size_t)64 * KPB;
    const unsigned char* gb0 = Wbt + (size_t)(d0 + srow) * KPB + (size_t)(ks + koct * 8) * 2;
    const unsigned char* gb1 = gb0 + (size_t)64 * KPB;
    unsigned char* la0 = &As[tid * 16];
    unsigned char* la1 = &As[4096 + tid * 16];
    unsigned char* lb0 = &Bs[tid * 16];
    unsigned char* lb1 = &Bs[4096 + tid * 16];

    f4v acc[4][4];
    #pragma unroll
    for (int a = 0; a < 4; a++)
        #pragma unroll
        for (int b = 0; b < 4; b++) acc[a][b] = (f4v)0.f;

    #pragma unroll 1
    for (int it = 0; it < NIT2; it++) {
        gl_lds16(ga0, la0);
        gl_lds16(ga1, la1);
        gl_lds16(gb0, lb0);
        gl_lds16(gb1, lb1);
        ga0 += 64; ga1 += 64; gb0 += 64; gb1 += 64;
        __syncthreads();                 // drains vmcnt -> LDS tile complete

        s8v af[4], bfr[4];
        #pragma unroll
        for (int mi = 0; mi < 4; mi++)
            af[mi] = *(const s8v*)&As[(wm + mi * 16 + l15) * 64 + l4 * 16];
        #pragma unroll
        for (int ni = 0; ni < 4; ni++)
            bfr[ni] = *(const s8v*)&Bs[(wn + ni * 16 + l15) * 64 + l4 * 16];
        #pragma unroll
        for (int mi = 0; mi < 4; mi++)
            #pragma unroll
            for (int ni = 0; ni < 4; ni++)
                acc[mi][ni] = __builtin_amdgcn_mfma_f32_16x16x32_bf16(
                    af[mi], bfr[ni], acc[mi][ni], 0, 0, 0);
        __syncthreads();                 // all reads done before next staging
    }

    float* dst = part + (size_t)s * SLICE;
    #pragma unroll
    for (int mi = 0; mi < 4; mi++) {
        #pragma unroll
        for (int ni = 0; ni < 4; ni++) {
            int col = d0 + wn + ni * 16 + l15;
            #pragma unroll
            for (int r = 0; r < 4; r++) {
                int row = i0 + wm + mi * 16 + l4 * 4 + r;
                dst[row * D_ + col] = acc[mi][ni][r];
            }
        }
    }
}

// ---------------- Path B/C GEMM (R4, known-correct fallback) ----------------
__launch_bounds__(256)
__global__ void gemm_kernel(const float* __restrict__ X,
                            const float* __restrict__ W,
                            float* __restrict__ part,
                            int use_atomic) {
    __shared__ __align__(16) short As[128 * LDA];
    __shared__ __align__(16) short Bs[128 * LDB];

    const int bx   = blockIdx.x;
    const int tile = bx & 15;
    const int s    = bx >> 4;
    const int i0   = (tile & 3) * 128;
    const int d0   = (tile >> 2) * 128;
    const int ks   = s * KC;
    const int ke   = min(ks + KC, V_);

    const int tid  = threadIdx.x;
    const int lane = tid & 63;
    const int wave = tid >> 6;
    const int wm   = (wave & 1) * 64;
    const int wn   = (wave >> 1) * 64;
    const int l15  = lane & 15;
    const int l4   = lane >> 4;

    const int ar   = tid >> 1;
    const int akh  = (tid & 1) * 16;
    const int bn2  = (tid & 63) * 2;
    const int bkq  = (tid >> 6) * 8;

    f4v acc[4][4];
    #pragma unroll
    for (int a = 0; a < 4; a++)
        #pragma unroll
        for (int b = 0; b < 4; b++) acc[a][b] = (f4v)0.f;

    auto stageA = [&](const float4 (&ab)[4]) {
        const float* f = (const float*)&ab[0];
        unsigned int au[8];
        #pragma unroll
        for (int p = 0; p < 8; p++)
            au[p] = pack2bf(__expf(f[2 * p]), __expf(f[2 * p + 1]));
        *(uint4*)&As[ar * LDA + akh]     = *(const uint4*)&au[0];
        *(uint4*)&As[ar * LDA + akh + 8] = *(const uint4*)&au[4];
    };
    auto stageB = [&](const float2 (&bb)[8]) {
        unsigned int r0[4], r1[4];
        #pragma unroll
        for (int p = 0; p < 4; p++) {
            r0[p] = pack2bf(bb[2 * p].x, bb[2 * p + 1].x);
            r1[p] = pack2bf(bb[2 * p].y, bb[2 * p + 1].y);
        }
        *(uint4*)&Bs[bn2 * LDB + bkq]       = *(const uint4*)&r0[0];
        *(uint4*)&Bs[(bn2 + 1) * LDB + bkq] = *(const uint4*)&r1[0];
    };
    auto domfma = [&]() {
        s8v af[4], bfr[4];
        #pragma unroll
        for (int mi = 0; mi < 4; mi++)
            af[mi] = *(const s8v*)&As[(wm + mi * 16 + l15) * LDA + l4 * 8];
        #pragma unroll
        for (int ni = 0; ni < 4; ni++)
            bfr[ni] = *(const s8v*)&Bs[(wn + ni * 16 + l15) * LDB + l4 * 8];
        #pragma unroll
        for (int mi = 0; mi < 4; mi++)
            #pragma unroll
            for (int ni = 0; ni < 4; ni++)
                acc[mi][ni] = __builtin_amdgcn_mfma_f32_16x16x32_bf16(
                    af[mi], bfr[ni], acc[mi][ni], 0, 0, 0);
    };
    auto issue = [&](float4 (&ab)[4], float2 (&bb)[8], const float* ap, const float* bp) {
        #pragma unroll
        for (int q = 0; q < 4; q++) ab[q] = *(const float4*)(ap + q * 4);
        #pragma unroll
        for (int j = 0; j < 8; j++) bb[j] = *(const float2*)(bp + (size_t)j * D_);
    };

    if (ks + KC <= V_) {
        const float* ap = X + (size_t)(i0 + ar) * V_ + ks + akh;
        const float* bp = W + d0 + bn2 + (size_t)(ks + bkq) * D_;
        float4 a0[4], a1[4];
        float2 b0[8], b1[8];
        issue(a0, b0, ap, bp);
        #pragma unroll 1
        for (int it = 0; it < NIT; it += 2) {
            ap += BK; bp += (size_t)BK * D_;
            if (it + 1 < NIT) issue(a1, b1, ap, bp);
            __syncthreads();
            stageA(a0); stageB(b0);
            __syncthreads();
            domfma();

            ap += BK; bp += (size_t)BK * D_;
            if (it + 2 < NIT) issue(a0, b0, ap, bp);
            __syncthreads();
            stageA(a1); stageB(b1);
            __syncthreads();
            domfma();
        }
    } else {
        const float* Abase = X + (size_t)(i0 + ar) * V_;
        const float* Bbase = W + d0 + bn2;
        for (int k0 = ks; k0 < ke; k0 += BK) {
            float4 ab[4];
            float2 bb[8];
            #pragma unroll
            for (int q = 0; q < 4; q++) {
                int gk = min(k0 + akh + q * 4, V_ - 4);
                ab[q] = *(const float4*)(Abase + gk);
            }
            #pragma unroll
            for (int j = 0; j < 8; j++) {
                int gk = min(k0 + bkq + j, V_ - 1);
                bb[j] = *(const float2*)(Bbase + (size_t)gk * D_);
            }
            __syncthreads();
            {
                unsigned int au[8];
                const float* f = (const float*)&ab[0];
                #pragma unroll
                for (int p = 0; p < 8; p++) {
                    int g0 = k0 + akh + 2 * p;
                    float e0 = (g0     < ke) ? __expf(f[2 * p])     : 0.f;
                    float e1 = (g0 + 1 < ke) ? __expf(f[2 * p + 1]) : 0.f;
                    au[p] = pack2bf(e0, e1);
                }
                *(uint4*)&As[ar * LDA + akh]     = *(const uint4*)&au[0];
                *(uint4*)&As[ar * LDA + akh + 8] = *(const uint4*)&au[4];
            }
            {
                unsigned int r0[4], r1[4];
                #pragma unroll
                for (int p = 0; p < 4; p++) {
                    int g0 = k0 + bkq + 2 * p;
                    float x0 = (g0     < ke) ? bb[2 * p].x     : 0.f;
                    float x1 = (g0 + 1 < ke) ? bb[2 * p + 1].x : 0.f;
                    float y0 = (g0     < ke) ? bb[2 * p].y     : 0.f;
                    float y1 = (g0 + 1 < ke) ? bb[2 * p + 1].y : 0.f;
                    r0[p] = pack2bf(x0, x1);
                    r1[p] = pack2bf(y0, y1);
                }
                *(uint4*)&Bs[bn2 * LDB + bkq]       = *(const uint4*)&r0[0];
                *(uint4*)&Bs[(bn2 + 1) * LDB + bkq] = *(const uint4*)&r1[0];
            }
            __syncthreads();
            domfma();
        }
    }

    float* dst = part + (use_atomic ? 0 : (size_t)s * SLICE);
    #pragma unroll
    for (int mi = 0; mi < 4; mi++) {
        #pragma unroll
        for (int ni = 0; ni < 4; ni++) {
            int col = d0 + wn + ni * 16 + l15;
            #pragma unroll
            for (int r = 0; r < 4; r++) {
                int row = i0 + wm + mi * 16 + l4 * 4 + r;
                if (use_atomic) atomicAdd(&dst[row * D_ + col], acc[mi][ni][r]);
                else            dst[row * D_ + col] = acc[mi][ni][r];
            }
        }
    }
}

// ---------------- ot: reduce nsl slices + mean_i cos(pred_i, W[trg_i]) --------
__global__ void ot_kernel(const float* __restrict__ part,
                          const float* __restrict__ W,
                          const int* __restrict__ trg,
                          float* __restrict__ acc,
                          int nsl) {
    int row  = blockIdx.x;
    int wv   = threadIdx.x >> 6, lane = threadIdx.x & 63;
    int d    = wv * 128 + lane * 2;
    const float* base = part + (size_t)row * D_ + d;
    float px = 0.f, py = 0.f;
    #pragma unroll 4
    for (int s2 = 0; s2 < nsl; s2++) {
        float2 q = *(const float2*)(base + (size_t)s2 * SLICE);
        px += q.x; py += q.y;
    }
    float2 t = *(const float2*)(W + (size_t)trg[row] * D_ + d);
    float dot = px * t.x + py * t.y;
    float nn  = px * px + py * py;
    float tt  = t.x * t.x + t.y * t.y;
    dot = wave_reduce(dot); nn = wave_reduce(nn); tt = wave_reduce(tt);
    __shared__ float red[3][4];
    if (lane == 0) { red[0][wv] = dot; red[1][wv] = nn; red[2][wv] = tt; }
    __syncthreads();
    if (threadIdx.x == 0) {
        dot = red[0][0] + red[0][1] + red[0][2] + red[0][3];
        nn  = red[1][0] + red[1][1] + red[1][2] + red[1][3];
        tt  = red[2][0] + red[2][1] + red[2][2] + red[2][3];
        atomicAdd(&acc[4], (dot / sqrtf(nn * tt)) * (1.0f / (float)NROWS));
    }
}

// ---------------- finalize ----------------
__global__ void finalize_kernel(const float* __restrict__ acc, float* __restrict__ out) {
    if (threadIdx.x == 0)
        out[0] = -acc[0] / acc[1] + acc[2] / acc[3] + GAMMA2_ + acc[4];
}

extern "C" void kernel_launch(void* const* d_in, const int* in_sizes, int n_in,
                              void* d_out, int out_size, void* d_ws, size_t ws_size,
                              hipStream_t stream) {
    const float* output_mle = (const float*)d_in[0];
    const float* attn       = (const float*)d_in[1];
    const float* cover      = (const float*)d_in[2];
    const int*   trg        = (const int*)d_in[3];
    const int*   dec_mask   = (const int*)d_in[4];
    const int*   dec_len    = (const int*)d_in[5];
    const float* W          = (const float*)d_in[6];
    float* out = (float*)d_out;
    float* acc = (float*)d_ws;

    if (ws_size >= NEED_A) {
        unsigned char* base = (unsigned char*)d_ws;
        uint4*        Eb    = (uint4*)(base + EB_OFF);
        unsigned int* Wbt   = (unsigned int*)(base + WBT_OFF);
        float*        part  = (float*)(base + PART2_OFF);

        hipMemsetAsync(d_ws, 0, 4096, stream);
        misc_kernel<<<65, 256, 0, stream>>>(output_mle, attn, cover, trg, dec_mask, dec_len, acc);
        conv_e_kernel<<<2048, 256, 0, stream>>>(output_mle, Eb);
        conv_w_kernel<<<(KP / 64) * (D_ / 64), 256, 0, stream>>>(W, Wbt);
        gemm2_kernel<<<16 * SPLITK2, 256, 0, stream>>>((const unsigned char*)Eb,
                                                       (const unsigned char*)Wbt, part);
        ot_kernel<<<NROWS, 256, 0, stream>>>(part, W, trg, acc, SPLITK2);
        finalize_kernel<<<1, 64, 0, stream>>>(acc, out);
    } else if (ws_size >= NEED_B) {
        float* part = acc + WS_PART_OFF;
        hipMemsetAsync(d_ws, 0, WS_PART_OFF * sizeof(float), stream);
        misc_kernel<<<65, 256, 0, stream>>>(output_mle, attn, cover, trg, dec_mask, dec_len, acc);
        gemm_kernel<<<16 * SPLITK, 256, 0, stream>>>(output_mle, W, part, 0);
        ot_kernel<<<NROWS, 256, 0, stream>>>(part, W, trg, acc, SPLITK);
        finalize_kernel<<<1, 64, 0, stream>>>(acc, out);
    } else {
        float* part = acc + WS_PART_OFF;
        hipMemsetAsync(d_ws, 0, (WS_PART_OFF + SLICE) * sizeof(float), stream);
        misc_kernel<<<65, 256, 0, stream>>>(output_mle, attn, cover, trg, dec_mask, dec_len, acc);
        gemm_kernel<<<16 * SPLITK, 256, 0, stream>>>(output_mle, W, part, 1);
        ot_kernel<<<NROWS, 256, 0, stream>>>(part, W, trg, acc, 1);
        finalize_kernel<<<1, 64, 0, stream>>>(acc, out);
    }
}